// Round 1
// 422.523 us; speedup vs baseline: 1.0986x; 1.0986x over previous
//
#include <hip/hip_runtime.h>
#include <math.h>

#define D_MODEL 1024
#define D_KEY 128
#define NSUB 256
#define NTOK 8192

typedef __attribute__((ext_vector_type(8))) short bf16x8;
typedef __attribute__((ext_vector_type(4))) float f32x4;

#define GLD16(g, l)                                                       \
  __builtin_amdgcn_global_load_lds(                                       \
      (const __attribute__((address_space(1))) void*)(g),                 \
      (__attribute__((address_space(3))) void*)(l), 16, 0, 0)

__device__ __forceinline__ unsigned short f2bf(float f) {
  union { float f; unsigned int u; } v; v.f = f;
  return (unsigned short)((v.u + 0x7fffu + ((v.u >> 16) & 1u)) >> 16);
}
__device__ __forceinline__ float bf2f(unsigned short u) {
  union { unsigned int u; float f; } v; v.u = ((unsigned int)u) << 16;
  return v.f;
}

// ---------------------------------------------------------------------------
// K0 (merged): blocks [0,4096) cast x f32 -> bf16 (xb).
//              blocks [4096,4224) build M_T[c][d] = sum_j Wq[joff+j][d]*keys[c&255][j]
// ---------------------------------------------------------------------------
__global__ __launch_bounds__(256) void k_cast_prep(const float* __restrict__ x,
                                                   unsigned short* __restrict__ xb,
                                                   const float* __restrict__ Wq,
                                                   const float* __restrict__ keys_a,
                                                   const float* __restrict__ keys_b,
                                                   unsigned short* __restrict__ Mt) {
  const int tid = threadIdx.x;
  if (blockIdx.x < 4096) {
    const size_t i0 = (size_t)blockIdx.x * 2048 + (size_t)tid * 8;
    const float4 a = *(const float4*)&x[i0];
    const float4 b = *(const float4*)&x[i0 + 4];
    bf16x8 o;
    o[0] = (short)f2bf(a.x); o[1] = (short)f2bf(a.y);
    o[2] = (short)f2bf(a.z); o[3] = (short)f2bf(a.w);
    o[4] = (short)f2bf(b.x); o[5] = (short)f2bf(b.y);
    o[6] = (short)f2bf(b.z); o[7] = (short)f2bf(b.w);
    *(bf16x8*)&xb[i0] = o;
    return;
  }
  __shared__ float ks[4][128];
  const int c0 = (blockIdx.x - 4096) * 4;
  const float* kk = (c0 < 256) ? keys_a : keys_b;
  const int rbase = c0 & 255;
  const int joff = (c0 < 256) ? 0 : 128;
  if (tid < 128) {
    const int r = tid >> 5, f = tid & 31;
    *(float4*)&ks[r][f * 4] = *(const float4*)&kk[(size_t)(rbase + r) * 128 + f * 4];
  }
  __syncthreads();
  const int d0 = tid * 4;
  float acc[4][4] = {};
  for (int j = 0; j < 128; j++) {
    const float4 wv = *(const float4*)&Wq[(size_t)(joff + j) * D_MODEL + d0];
#pragma unroll
    for (int r = 0; r < 4; r++) {
      const float kj = ks[r][j];
      acc[r][0] += wv.x * kj; acc[r][1] += wv.y * kj;
      acc[r][2] += wv.z * kj; acc[r][3] += wv.w * kj;
    }
  }
#pragma unroll
  for (int r = 0; r < 4; r++) {
    ushort4 o;
    o.x = f2bf(acc[r][0]); o.y = f2bf(acc[r][1]);
    o.z = f2bf(acc[r][2]); o.w = f2bf(acc[r][3]);
    *(ushort4*)&Mt[(size_t)(c0 + r) * D_MODEL + d0] = o;
  }
}

// ---------------------------------------------------------------------------
// K1: scores = xb[8192x1024] * Mt^T[1024x512] via bf16 MFMA, m97-style.
// Tile 64 tok x 128 col, BK=32, global_load_lds(16B) staging, 4 waves 32x64.
// Grid (4, 128).
// ---------------------------------------------------------------------------
__global__ __launch_bounds__(256) void k_scores(const unsigned short* __restrict__ xb,
                                                const unsigned short* __restrict__ Mt,
                                                unsigned short* __restrict__ scores) {
  __shared__ __align__(16) short As[64 * 32];    // [tok][k]
  __shared__ __align__(16) short Bs[128 * 32];   // [col][k]
  const int tid = threadIdx.x;
  const int t0 = blockIdx.y * 64;
  const int c0 = blockIdx.x * 128;
  const int l = tid & 63, w = tid >> 6;
  const int rw0 = (w & 1) * 32;
  const int cw0 = (w >> 1) * 64;
  const int fr = l & 15, q = l >> 4;

  // staging geometry: 16B chunk c -> row c>>2, seg c&3 (8 bf16). LDS dest is
  // wave-uniform base + lane*16 (linear), so chunk index == w*64 + lane.
  const int sr = tid >> 2, sseg = (tid & 3) * 8;
  const unsigned short* agp = xb + (size_t)(t0 + sr) * D_MODEL + sseg;
  const unsigned short* bgp0 = Mt + (size_t)(c0 + sr) * D_MODEL + sseg;
  const unsigned short* bgp1 = Mt + (size_t)(c0 + 64 + sr) * D_MODEL + sseg;
  short* ald = As + w * 512;           // uniform per wave
  short* bld0 = Bs + w * 512;
  short* bld1 = Bs + 2048 + w * 512;

  f32x4 acc[2][4];
#pragma unroll
  for (int mi = 0; mi < 2; mi++)
#pragma unroll
    for (int ni = 0; ni < 4; ni++) acc[mi][ni] = (f32x4){0.f, 0.f, 0.f, 0.f};

  for (int kc = 0; kc < D_MODEL; kc += 32) {
    GLD16(agp + kc, ald);
    GLD16(bgp0 + kc, bld0);
    GLD16(bgp1 + kc, bld1);
    __syncthreads();   // compiler emits vmcnt(0) drain before barrier
    bf16x8 af[2], bfr[4];
#pragma unroll
    for (int mi = 0; mi < 2; mi++)
      af[mi] = *(const bf16x8*)&As[(rw0 + mi * 16 + fr) * 32 + q * 8];
#pragma unroll
    for (int ni = 0; ni < 4; ni++)
      bfr[ni] = *(const bf16x8*)&Bs[(cw0 + ni * 16 + fr) * 32 + q * 8];
#pragma unroll
    for (int mi = 0; mi < 2; mi++)
#pragma unroll
      for (int ni = 0; ni < 4; ni++)
        acc[mi][ni] = __builtin_amdgcn_mfma_f32_16x16x32_bf16(af[mi], bfr[ni], acc[mi][ni], 0, 0, 0);
    __syncthreads();
  }
#pragma unroll
  for (int mi = 0; mi < 2; mi++)
#pragma unroll
    for (int ni = 0; ni < 4; ni++)
#pragma unroll
      for (int r = 0; r < 4; r++) {
        const int row = t0 + rw0 + mi * 16 + q * 4 + r;
        const int col = c0 + cw0 + ni * 16 + fr;
        scores[(size_t)row * 512 + col] = f2bf(acc[mi][ni][r]);
      }
}

// ---------------------------------------------------------------------------
// K2 (fused): one WAVE per token, no LDS, no barriers.
// Packed-u32 argmax: key = monotone(bf16)<<16 | (idx^255). One shfl + one
// u32-max per butterfly level; ties resolve to lowest index (top_k semantics).
// Winner state lives in per-lane registers (no runtime-indexed arrays ->
// no scratch). Then softmax + full-row coalesced gather + gate + residual.
// ---------------------------------------------------------------------------
__global__ __launch_bounds__(256) void k_topk_gather(const unsigned short* __restrict__ scores,
                                                     const float* __restrict__ x,
                                                     const float* __restrict__ values,
                                                     const float* __restrict__ gate_w,
                                                     const float* __restrict__ gate_b,
                                                     float* __restrict__ out) {
  const int tid = threadIdx.x;
  const int lane = tid & 63;
  const size_t t = (size_t)blockIdx.x * 4 + (tid >> 6);

  const unsigned short* srow = scores + t * 512;
  const ushort4 ra = *(const ushort4*)&srow[lane * 4];
  const ushort4 rb = *(const ushort4*)&srow[256 + lane * 4];

  unsigned pa[4], pb[4];
  {
    const unsigned short av[4] = {ra.x, ra.y, ra.z, ra.w};
    const unsigned short bw[4] = {rb.x, rb.y, rb.z, rb.w};
#pragma unroll
    for (int c = 0; c < 4; c++) {
      unsigned ma = av[c];
      ma = (ma & 0x8000u) ? (ma ^ 0xFFFFu) : (ma | 0x8000u);
      pa[c] = (ma << 16) | (unsigned)((lane * 4 + c) ^ 255);
      unsigned mb = bw[c];
      mb = (mb & 0x8000u) ? (mb ^ 0xFFFFu) : (mb | 0x8000u);
      pb[c] = (mb << 16) | (unsigned)((lane * 4 + c) ^ 255);
    }
  }

  float myAv = 0.f, myBv = 0.f;
  int myAi = 0, myBi = 0;
  // top-8 of A-scores; winner #sel parked in lanes with lane>>3 == sel
#pragma unroll
  for (int sel = 0; sel < 8; sel++) {
    unsigned m0 = pa[0] > pa[1] ? pa[0] : pa[1];
    unsigned m1 = pa[2] > pa[3] ? pa[2] : pa[3];
    unsigned bv = m0 > m1 ? m0 : m1;
#pragma unroll
    for (int off = 32; off >= 1; off >>= 1) {
      const unsigned ov = __shfl_xor(bv, off);
      bv = ov > bv ? ov : bv;
    }
    const int widx = (int)(bv & 255u) ^ 255;
    const unsigned mk = bv >> 16;
    const unsigned sb = (mk & 0x8000u) ? (mk ^ 0x8000u) : (mk ^ 0xFFFFu);
    if ((lane >> 3) == sel) { myAv = bf2f((unsigned short)sb); myAi = widx; }
#pragma unroll
    for (int c = 0; c < 4; c++)
      if (widx == lane * 4 + c) pa[c] = 0u;
  }
  // top-8 of B-scores; winner #sel parked in lanes with (lane&7) == sel
#pragma unroll
  for (int sel = 0; sel < 8; sel++) {
    unsigned m0 = pb[0] > pb[1] ? pb[0] : pb[1];
    unsigned m1 = pb[2] > pb[3] ? pb[2] : pb[3];
    unsigned bv = m0 > m1 ? m0 : m1;
#pragma unroll
    for (int off = 32; off >= 1; off >>= 1) {
      const unsigned ov = __shfl_xor(bv, off);
      bv = ov > bv ? ov : bv;
    }
    const int widx = (int)(bv & 255u) ^ 255;
    const unsigned mk = bv >> 16;
    const unsigned sb = (mk & 0x8000u) ? (mk ^ 0x8000u) : (mk ^ 0xFFFFu);
    if ((lane & 7) == sel) { myBv = bf2f((unsigned short)sb); myBi = widx; }
#pragma unroll
    for (int c = 0; c < 4; c++)
      if (widx == lane * 4 + c) pb[c] = 0u;
  }

  // 64 combined candidates, lane = i*8 + j (flat row-major order).
  const float cvv = myAv + myBv;
  const int abidx = myAi * NSUB + myBi;
  unsigned cu = __float_as_uint(cvv);
  cu = ((int)cu < 0) ? ~cu : (cu | 0x80000000u);
  unsigned pc = (cu & 0xFFFFFFC0u) | (unsigned)(lane ^ 63);

  float fv[8]; int fidx[8];
#pragma unroll
  for (int sel = 0; sel < 8; sel++) {
    unsigned bv = pc;
#pragma unroll
    for (int off = 32; off >= 1; off >>= 1) {
      const unsigned ov = __shfl_xor(bv, off);
      bv = ov > bv ? ov : bv;
    }
    const int bl = (int)(bv & 63u) ^ 63;
    fv[sel] = __shfl(cvv, bl);
    fidx[sel] = __shfl(abidx, bl);
    if (lane == bl) pc = 0u;
  }

  // softmax over 8 (fv[0] is the max; uniform across lanes)
  float wgt[8]; float ssum = 0.f;
#pragma unroll
  for (int k = 0; k < 8; k++) { wgt[k] = __expf(fv[k] - fv[0]); ssum += wgt[k]; }
  const float inv = 1.0f / ssum;
#pragma unroll
  for (int k = 0; k < 8; k++) wgt[k] *= inv;

  // gather phase: lane covers dims {i*256 + lane*4}, fully coalesced (1KB/inst)
  const float* xr = x + t * D_MODEL;
  float4 xv[4], gw[4];
#pragma unroll
  for (int i = 0; i < 4; i++) {
    xv[i] = *(const float4*)&xr[i * 256 + lane * 4];
    gw[i] = *(const float4*)&gate_w[i * 256 + lane * 4];
  }
  float gp = 0.f;
#pragma unroll
  for (int i = 0; i < 4; i++)
    gp += xv[i].x * gw[i].x + xv[i].y * gw[i].y + xv[i].z * gw[i].z + xv[i].w * gw[i].w;
#pragma unroll
  for (int off = 32; off >= 1; off >>= 1) gp += __shfl_xor(gp, off);
  const float g = 1.0f / (1.0f + __expf(-(gp + gate_b[0])));

  float4 acc[4];
#pragma unroll
  for (int i = 0; i < 4; i++) acc[i] = make_float4(0.f, 0.f, 0.f, 0.f);
#pragma unroll
  for (int k = 0; k < 8; k++) {
    const float wk = wgt[k];
    const float* vr = values + (size_t)fidx[k] * D_MODEL;
#pragma unroll
    for (int i = 0; i < 4; i++) {
      const float4 v = *(const float4*)&vr[i * 256 + lane * 4];
      acc[i].x += wk * v.x; acc[i].y += wk * v.y;
      acc[i].z += wk * v.z; acc[i].w += wk * v.w;
    }
  }
  float* orow = out + t * D_MODEL;
#pragma unroll
  for (int i = 0; i < 4; i++) {
    float4 o;
    o.x = xv[i].x + g * acc[i].x; o.y = xv[i].y + g * acc[i].y;
    o.z = xv[i].z + g * acc[i].z; o.w = xv[i].w + g * acc[i].w;
    *(float4*)&orow[i * 256 + lane * 4] = o;
  }
}

extern "C" void kernel_launch(void* const* d_in, const int* in_sizes, int n_in,
                              void* d_out, int out_size, void* d_ws, size_t ws_size,
                              hipStream_t stream) {
  const float* x = (const float*)d_in[0];
  const float* keys_a = (const float*)d_in[1];
  const float* keys_b = (const float*)d_in[2];
  const float* values = (const float*)d_in[3];
  const float* Wq = (const float*)d_in[4];
  const float* gate_w = (const float*)d_in[5];
  const float* gate_b = (const float*)d_in[6];
  float* out = (float*)d_out;

  char* ws = (char*)d_ws;
  unsigned short* scores = (unsigned short*)ws;                                  // 8 MB
  unsigned short* Mt = (unsigned short*)(ws + (size_t)8 * 1024 * 1024);          // 1 MB
  unsigned short* xb = (unsigned short*)(ws + (size_t)9 * 1024 * 1024);          // 16 MB

  k_cast_prep<<<4224, 256, 0, stream>>>(x, xb, Wq, keys_a, keys_b, Mt);
  k_scores<<<dim3(4, 128), 256, 0, stream>>>(xb, Mt, scores);
  k_topk_gather<<<NTOK / 4, 256, 0, stream>>>(scores, x, values, gate_w, gate_b, out);
}

// Round 4
// 421.295 us; speedup vs baseline: 1.1018x; 1.0029x over previous
//
#include <hip/hip_runtime.h>
#include <math.h>

#define D_MODEL 1024
#define D_KEY 128
#define NSUB 256
#define NTOK 8192

typedef __attribute__((ext_vector_type(8))) short bf16x8;
typedef __attribute__((ext_vector_type(4))) float f32x4;

#define GLD16(g, l)                                                       \
  __builtin_amdgcn_global_load_lds(                                       \
      (const __attribute__((address_space(1))) void*)(g),                 \
      (__attribute__((address_space(3))) void*)(l), 16, 0, 0)

__device__ __forceinline__ unsigned short f2bf(float f) {
  union { float f; unsigned int u; } v; v.f = f;
  return (unsigned short)((v.u + 0x7fffu + ((v.u >> 16) & 1u)) >> 16);
}
__device__ __forceinline__ float bf2f(unsigned short u) {
  union { unsigned int u; float f; } v; v.u = ((unsigned int)u) << 16;
  return v.f;
}

// ---------------------------------------------------------------------------
// K0 (merged): blocks [0,4096) cast x f32 -> bf16 (xb).
//              blocks [4096,4224) build M_T[c][d] = sum_j Wq[joff+j][d]*keys[c&255][j]
// ---------------------------------------------------------------------------
__global__ __launch_bounds__(256) void k_cast_prep(const float* __restrict__ x,
                                                   unsigned short* __restrict__ xb,
                                                   const float* __restrict__ Wq,
                                                   const float* __restrict__ keys_a,
                                                   const float* __restrict__ keys_b,
                                                   unsigned short* __restrict__ Mt) {
  const int tid = threadIdx.x;
  if (blockIdx.x < 4096) {
    const size_t i0 = (size_t)blockIdx.x * 2048 + (size_t)tid * 8;
    const float4 a = *(const float4*)&x[i0];
    const float4 b = *(const float4*)&x[i0 + 4];
    bf16x8 o;
    o[0] = (short)f2bf(a.x); o[1] = (short)f2bf(a.y);
    o[2] = (short)f2bf(a.z); o[3] = (short)f2bf(a.w);
    o[4] = (short)f2bf(b.x); o[5] = (short)f2bf(b.y);
    o[6] = (short)f2bf(b.z); o[7] = (short)f2bf(b.w);
    *(bf16x8*)&xb[i0] = o;
    return;
  }
  __shared__ float ks[4][128];
  const int c0 = (blockIdx.x - 4096) * 4;
  const float* kk = (c0 < 256) ? keys_a : keys_b;
  const int rbase = c0 & 255;
  const int joff = (c0 < 256) ? 0 : 128;
  if (tid < 128) {
    const int r = tid >> 5, f = tid & 31;
    *(float4*)&ks[r][f * 4] = *(const float4*)&kk[(size_t)(rbase + r) * 128 + f * 4];
  }
  __syncthreads();
  const int d0 = tid * 4;
  float acc[4][4] = {};
  for (int j = 0; j < 128; j++) {
    const float4 wv = *(const float4*)&Wq[(size_t)(joff + j) * D_MODEL + d0];
#pragma unroll
    for (int r = 0; r < 4; r++) {
      const float kj = ks[r][j];
      acc[r][0] += wv.x * kj; acc[r][1] += wv.y * kj;
      acc[r][2] += wv.z * kj; acc[r][3] += wv.w * kj;
    }
  }
#pragma unroll
  for (int r = 0; r < 4; r++) {
    ushort4 o;
    o.x = f2bf(acc[r][0]); o.y = f2bf(acc[r][1]);
    o.z = f2bf(acc[r][2]); o.w = f2bf(acc[r][3]);
    *(ushort4*)&Mt[(size_t)(c0 + r) * D_MODEL + d0] = o;
  }
}

// ---------------------------------------------------------------------------
// K1: scores = xb[8192x1024] * Mt^T[1024x512] via bf16 MFMA, m97-style.
// Tile 64 tok x 128 col, BK=32, global_load_lds(16B) staging, 4 waves 32x64.
// Grid (4, 128). (Round-1-proven single-buffer structure.)
// ---------------------------------------------------------------------------
__global__ __launch_bounds__(256) void k_scores(const unsigned short* __restrict__ xb,
                                                const unsigned short* __restrict__ Mt,
                                                unsigned short* __restrict__ scores) {
  __shared__ __align__(16) short As[64 * 32];    // [tok][k]
  __shared__ __align__(16) short Bs[128 * 32];   // [col][k]
  const int tid = threadIdx.x;
  const int t0 = blockIdx.y * 64;
  const int c0 = blockIdx.x * 128;
  const int l = tid & 63, w = tid >> 6;
  const int rw0 = (w & 1) * 32;
  const int cw0 = (w >> 1) * 64;
  const int fr = l & 15, q = l >> 4;

  // staging geometry: 16B chunk c -> row c>>2, seg c&3 (8 bf16). LDS dest is
  // wave-uniform base + lane*16 (linear), so chunk index == w*64 + lane.
  const int sr = tid >> 2, sseg = (tid & 3) * 8;
  const unsigned short* agp = xb + (size_t)(t0 + sr) * D_MODEL + sseg;
  const unsigned short* bgp0 = Mt + (size_t)(c0 + sr) * D_MODEL + sseg;
  const unsigned short* bgp1 = Mt + (size_t)(c0 + 64 + sr) * D_MODEL + sseg;
  short* ald = As + w * 512;           // uniform per wave
  short* bld0 = Bs + w * 512;
  short* bld1 = Bs + 2048 + w * 512;

  f32x4 acc[2][4];
#pragma unroll
  for (int mi = 0; mi < 2; mi++)
#pragma unroll
    for (int ni = 0; ni < 4; ni++) acc[mi][ni] = (f32x4){0.f, 0.f, 0.f, 0.f};

  for (int kc = 0; kc < D_MODEL; kc += 32) {
    GLD16(agp + kc, ald);
    GLD16(bgp0 + kc, bld0);
    GLD16(bgp1 + kc, bld1);
    __syncthreads();   // compiler emits vmcnt(0) drain before barrier
    bf16x8 af[2], bfr[4];
#pragma unroll
    for (int mi = 0; mi < 2; mi++)
      af[mi] = *(const bf16x8*)&As[(rw0 + mi * 16 + fr) * 32 + q * 8];
#pragma unroll
    for (int ni = 0; ni < 4; ni++)
      bfr[ni] = *(const bf16x8*)&Bs[(cw0 + ni * 16 + fr) * 32 + q * 8];
#pragma unroll
    for (int mi = 0; mi < 2; mi++)
#pragma unroll
      for (int ni = 0; ni < 4; ni++)
        acc[mi][ni] = __builtin_amdgcn_mfma_f32_16x16x32_bf16(af[mi], bfr[ni], acc[mi][ni], 0, 0, 0);
    __syncthreads();
  }
#pragma unroll
  for (int mi = 0; mi < 2; mi++)
#pragma unroll
    for (int ni = 0; ni < 4; ni++)
#pragma unroll
      for (int r = 0; r < 4; r++) {
        const int row = t0 + rw0 + mi * 16 + q * 4 + r;
        const int col = c0 + cw0 + ni * 16 + fr;
        scores[(size_t)row * 512 + col] = f2bf(acc[mi][ni][r]);
      }
}

// ---------------------------------------------------------------------------
// K2 (fused): one WAVE per token, no LDS, no barriers.
// Packed-u32 argmax (1 shfl + 1 u32-max per level; ties -> lowest index).
// A/B extraction chains interleaved (2x ILP on the dependent-shfl path).
// Combine winners decoded directly from packed bits (no value shfl).
// x / gate_w loads hoisted above the chain to overlap HBM latency.
// ---------------------------------------------------------------------------
__global__ __launch_bounds__(256) void k_topk_gather(const unsigned short* __restrict__ scores,
                                                     const float* __restrict__ x,
                                                     const float* __restrict__ values,
                                                     const float* __restrict__ gate_w,
                                                     const float* __restrict__ gate_b,
                                                     float* __restrict__ out) {
  const int tid = threadIdx.x;
  const int lane = tid & 63;
  const size_t t = (size_t)blockIdx.x * 4 + (tid >> 6);

  // hoisted row loads (independent of top-k chain)
  const float* xr = x + t * D_MODEL;
  float4 xv[4], gw[4];
#pragma unroll
  for (int i = 0; i < 4; i++) {
    xv[i] = *(const float4*)&xr[i * 256 + lane * 4];
    gw[i] = *(const float4*)&gate_w[i * 256 + lane * 4];
  }

  const unsigned short* srow = scores + t * 512;
  const ushort4 ra = *(const ushort4*)&srow[lane * 4];
  const ushort4 rb = *(const ushort4*)&srow[256 + lane * 4];

  unsigned pa[4], pb[4];
  {
    const unsigned short av[4] = {ra.x, ra.y, ra.z, ra.w};
    const unsigned short bw[4] = {rb.x, rb.y, rb.z, rb.w};
#pragma unroll
    for (int c = 0; c < 4; c++) {
      unsigned ma = av[c];
      ma = (ma & 0x8000u) ? (ma ^ 0xFFFFu) : (ma | 0x8000u);
      pa[c] = (ma << 16) | (unsigned)((lane * 4 + c) ^ 255);
      unsigned mb = bw[c];
      mb = (mb & 0x8000u) ? (mb ^ 0xFFFFu) : (mb | 0x8000u);
      pb[c] = (mb << 16) | (unsigned)((lane * 4 + c) ^ 255);
    }
  }

  float myAv = 0.f, myBv = 0.f;
  int myAi = 0, myBi = 0;
  // top-8 of A and B, chains interleaved. A-winner #sel parked in lanes with
  // lane>>3 == sel; B-winner #sel in lanes with (lane&7) == sel.
#pragma unroll
  for (int sel = 0; sel < 8; sel++) {
    unsigned a0 = pa[0] > pa[1] ? pa[0] : pa[1];
    unsigned a1 = pa[2] > pa[3] ? pa[2] : pa[3];
    unsigned bvA = a0 > a1 ? a0 : a1;
    unsigned b0 = pb[0] > pb[1] ? pb[0] : pb[1];
    unsigned b1 = pb[2] > pb[3] ? pb[2] : pb[3];
    unsigned bvB = b0 > b1 ? b0 : b1;
#pragma unroll
    for (int off = 32; off >= 1; off >>= 1) {
      const unsigned oa = __shfl_xor(bvA, off);
      const unsigned ob = __shfl_xor(bvB, off);
      bvA = oa > bvA ? oa : bvA;
      bvB = ob > bvB ? ob : bvB;
    }
    const int wiA = (int)(bvA & 255u) ^ 255;
    const unsigned mkA = bvA >> 16;
    const unsigned sbA = (mkA & 0x8000u) ? (mkA ^ 0x8000u) : (mkA ^ 0xFFFFu);
    if ((lane >> 3) == sel) { myAv = bf2f((unsigned short)sbA); myAi = wiA; }
    const int wiB = (int)(bvB & 255u) ^ 255;
    const unsigned mkB = bvB >> 16;
    const unsigned sbB = (mkB & 0x8000u) ? (mkB ^ 0x8000u) : (mkB ^ 0xFFFFu);
    if ((lane & 7) == sel) { myBv = bf2f((unsigned short)sbB); myBi = wiB; }
#pragma unroll
    for (int c = 0; c < 4; c++) {
      if (wiA == lane * 4 + c) pa[c] = 0u;
      if (wiB == lane * 4 + c) pb[c] = 0u;
    }
  }

  // 64 combined candidates, lane = i*8 + j (flat row-major order).
  const float cvv = myAv + myBv;
  const int abidx = myAi * NSUB + myBi;
  unsigned cu = __float_as_uint(cvv);
  cu = ((int)cu < 0) ? ~cu : (cu | 0x80000000u);
  unsigned pc = (cu & 0xFFFFFFC0u) | (unsigned)(lane ^ 63);

  float fv[8]; int fidx[8];
#pragma unroll
  for (int sel = 0; sel < 8; sel++) {
    unsigned bv = pc;
#pragma unroll
    for (int off = 32; off >= 1; off >>= 1) {
      const unsigned ov = __shfl_xor(bv, off);
      bv = ov > bv ? ov : bv;
    }
    const int bl = (int)(bv & 63u) ^ 63;
    // decode value straight from packed bits (low 6 mantissa bits zeroed:
    // rel err 2^-18, far below the bf16 quantization already in scores)
    const unsigned orig = (bv & 0x80000000u) ? (bv & 0x7FFFFFC0u)
                                             : ((~bv) & 0xFFFFFFC0u);
    fv[sel] = __uint_as_float(orig);
    fidx[sel] = __shfl(abidx, bl);
    if (lane == bl) pc = 0u;
  }

  // softmax over 8 (fv[0] is the max; uniform across lanes)
  float wgt[8]; float ssum = 0.f;
#pragma unroll
  for (int k = 0; k < 8; k++) { wgt[k] = __expf(fv[k] - fv[0]); ssum += wgt[k]; }
  const float inv = 1.0f / ssum;
#pragma unroll
  for (int k = 0; k < 8; k++) wgt[k] *= inv;

  // gate dot + reduce
  float gp = 0.f;
#pragma unroll
  for (int i = 0; i < 4; i++)
    gp += xv[i].x * gw[i].x + xv[i].y * gw[i].y + xv[i].z * gw[i].z + xv[i].w * gw[i].w;
#pragma unroll
  for (int off = 32; off >= 1; off >>= 1) gp += __shfl_xor(gp, off);
  const float g = 1.0f / (1.0f + __expf(-(gp + gate_b[0])));

  // gather: lane covers dims {i*256 + lane*4}, fully coalesced (1KB/inst)
  float4 acc[4];
#pragma unroll
  for (int i = 0; i < 4; i++) acc[i] = make_float4(0.f, 0.f, 0.f, 0.f);
#pragma unroll
  for (int k = 0; k < 8; k++) {
    const float wk = wgt[k];
    const float* vr = values + (size_t)fidx[k] * D_MODEL;
#pragma unroll
    for (int i = 0; i < 4; i++) {
      const float4 v = *(const float4*)&vr[i * 256 + lane * 4];
      acc[i].x += wk * v.x; acc[i].y += wk * v.y;
      acc[i].z += wk * v.z; acc[i].w += wk * v.w;
    }
  }
  float* orow = out + t * D_MODEL;
#pragma unroll
  for (int i = 0; i < 4; i++) {
    float4 o;
    o.x = xv[i].x + g * acc[i].x; o.y = xv[i].y + g * acc[i].y;
    o.z = xv[i].z + g * acc[i].z; o.w = xv[i].w + g * acc[i].w;
    *(float4*)&orow[i * 256 + lane * 4] = o;
  }
}

extern "C" void kernel_launch(void* const* d_in, const int* in_sizes, int n_in,
                              void* d_out, int out_size, void* d_ws, size_t ws_size,
                              hipStream_t stream) {
  const float* x = (const float*)d_in[0];
  const float* keys_a = (const float*)d_in[1];
  const float* keys_b = (const float*)d_in[2];
  const float* values = (const float*)d_in[3];
  const float* Wq = (const float*)d_in[4];
  const float* gate_w = (const float*)d_in[5];
  const float* gate_b = (const float*)d_in[6];
  float* out = (float*)d_out;

  char* ws = (char*)d_ws;
  unsigned short* scores = (unsigned short*)ws;                                  // 8 MB
  unsigned short* Mt = (unsigned short*)(ws + (size_t)8 * 1024 * 1024);          // 1 MB
  unsigned short* xb = (unsigned short*)(ws + (size_t)9 * 1024 * 1024);          // 16 MB

  k_cast_prep<<<4224, 256, 0, stream>>>(x, xb, Wq, keys_a, keys_b, Mt);
  k_scores<<<dim3(4, 128), 256, 0, stream>>>(xb, Mt, scores);
  k_topk_gather<<<NTOK / 4, 256, 0, stream>>>(scores, x, values, gate_w, gate_b, out);
}